// Round 2
// baseline (92.881 us; speedup 1.0000x reference)
//
#include <hip/hip_runtime.h>

#define CUBIC_A (-0.75f)

__device__ __forceinline__ float cubic_w(float d) {
    float ad = fabsf(d);
    if (ad <= 1.0f) return ((CUBIC_A + 2.0f) * ad - (CUBIC_A + 3.0f)) * ad * ad + 1.0f;
    if (ad < 2.0f)  return CUBIC_A * (((ad - 5.0f) * ad + 8.0f) * ad - 4.0f);
    return 0.0f;
}

// Compile-time frame count T -> fully unrolled loop: all T x-loads issued
// before any use (8x memory-level parallelism per wave vs runtime loop).
template <int T>
__device__ __forceinline__ void add_frames(const float4* __restrict__ x,
                                           const float4* __restrict__ tw,
                                           float4* __restrict__ out,
                                           size_t rowbase, int ppf, int px, int d4,
                                           float4 pe) {
    const size_t base = (rowbase + (size_t)px) * 256 + d4;
    const size_t fstride = (size_t)ppf * 256;
    float4 xv[T];
#pragma unroll
    for (int f = 0; f < T; ++f) xv[f] = x[base + (size_t)f * fstride];
    if (T > 1) {
        float4 tv[T];
#pragma unroll
        for (int f = 0; f < T; ++f) tv[f] = tw[(size_t)f * 256 + d4];
#pragma unroll
        for (int f = 0; f < T; ++f) {
            out[base + (size_t)f * fstride] =
                make_float4(xv[f].x + pe.x + tv[f].x,
                            xv[f].y + pe.y + tv[f].y,
                            xv[f].z + pe.z + tv[f].z,
                            xv[f].w + pe.w + tv[f].w);
        }
    } else {
        out[base] = make_float4(xv[0].x + pe.x, xv[0].y + pe.y,
                                xv[0].z + pe.z, xv[0].w + pe.w);
    }
}

__device__ __forceinline__ float4 bicubic_pe(const float4* __restrict__ wgt,
                                             int px, int out_hw, int d4) {
    const int i = px / out_hw;
    const int j = px % out_hw;
    const float scale = 64.0f / (float)out_hw;
    const float si = ((float)i + 0.5f) * scale - 0.5f;
    const float sj = ((float)j + 0.5f) * scale - 0.5f;
    const int i0 = (int)floorf(si);
    const int j0 = (int)floorf(sj);
    int ih[4], iw[4];
    float wh[4], ww[4];
#pragma unroll
    for (int a = 0; a < 4; ++a) {
        int tp = i0 - 1 + a;
        wh[a] = cubic_w(si - (float)tp);
        ih[a] = min(63, max(0, tp));
        tp = j0 - 1 + a;
        ww[a] = cubic_w(sj - (float)tp);
        iw[a] = min(63, max(0, tp));
    }
    float ax = 0.f, ay = 0.f, az = 0.f, aw = 0.f;
#pragma unroll
    for (int a = 0; a < 4; ++a) {
        float rx = 0.f, ry = 0.f, rz = 0.f, rw = 0.f;
#pragma unroll
        for (int c = 0; c < 4; ++c) {
            const float4 v = wgt[(size_t)(ih[a] * 64 + iw[c]) * 256 + d4];
            rx = fmaf(ww[c], v.x, rx);
            ry = fmaf(ww[c], v.y, ry);
            rz = fmaf(ww[c], v.z, rz);
            rw = fmaf(ww[c], v.w, rw);
        }
        ax = fmaf(wh[a], rx, ax);
        ay = fmaf(wh[a], ry, ay);
        az = fmaf(wh[a], rz, az);
        aw = fmaf(wh[a], rw, aw);
    }
    return make_float4(ax, ay, az, aw);
}

// GRIDS = [(8,32,32),(8,48,48),(4,64,64),(1,64,64)], weight (64,64,1024), dim=1024.
// One block per (grid, pixel); 256 threads; thread d4 owns float4 column d4.
__global__ __launch_bounds__(256) void posemb_add_kernel(
    const float4* __restrict__ x,     // (47104, 256) as float4
    const float4* __restrict__ wgt,   // (64*64, 256) as float4
    const float4* __restrict__ tw,    // (16, 256) as float4
    float4* __restrict__ out)         // (47104, 256) as float4
{
    const int b  = blockIdx.x;
    const int d4 = threadIdx.x;

    if (b < 1024) {              // (8,32,32), interp
        const int px = b;
        const float4 pe = bicubic_pe(wgt, px, 32, d4);
        add_frames<8>(x, tw, out, 0, 1024, px, d4, pe);
    } else if (b < 3328) {       // (8,48,48), interp
        const int px = b - 1024;
        const float4 pe = bicubic_pe(wgt, px, 48, d4);
        add_frames<8>(x, tw, out, 8192, 2304, px, d4, pe);
    } else if (b < 7424) {       // (4,64,64), direct
        const int px = b - 3328;
        const float4 pe = wgt[(size_t)px * 256 + d4];
        add_frames<4>(x, tw, out, 26624, 4096, px, d4, pe);
    } else {                     // (1,64,64), direct
        const int px = b - 7424;
        const float4 pe = wgt[(size_t)px * 256 + d4];
        add_frames<1>(x, tw, out, 43008, 4096, px, d4, pe);
    }
}

extern "C" void kernel_launch(void* const* d_in, const int* in_sizes, int n_in,
                              void* d_out, int out_size, void* d_ws, size_t ws_size,
                              hipStream_t stream) {
    const float4* x   = (const float4*)d_in[0];
    const float4* wgt = (const float4*)d_in[1];
    const float4* tw  = (const float4*)d_in[2];
    float4* out = (float4*)d_out;
    // 1024 + 2304 + 4096 + 4096 = 11520 pixel-blocks
    posemb_add_kernel<<<11520, 256, 0, stream>>>(x, wgt, tw, out);
}

// Round 3
// 78.247 us; speedup vs baseline: 1.1870x; 1.1870x over previous
//
#include <hip/hip_runtime.h>

#define CUBIC_A (-0.75f)

typedef float f4nt __attribute__((ext_vector_type(4)));

__device__ __forceinline__ void nt_store4(float4* p, float4 v) {
    f4nt t;
    t.x = v.x; t.y = v.y; t.z = v.z; t.w = v.w;
    __builtin_nontemporal_store(t, (f4nt*)p);
}

__device__ __forceinline__ float cubic_w(float d) {
    float ad = fabsf(d);
    if (ad <= 1.0f) return ((CUBIC_A + 2.0f) * ad - (CUBIC_A + 3.0f)) * ad * ad + 1.0f;
    if (ad < 2.0f)  return CUBIC_A * (((ad - 5.0f) * ad + 8.0f) * ad - 4.0f);
    return 0.0f;
}

template <int T>
__device__ __forceinline__ void add_frames(const float4* __restrict__ x,
                                           const float4* __restrict__ tw,
                                           float4* __restrict__ out,
                                           size_t rowbase, int ppf, int px, int d4,
                                           float4 pe) {
    const size_t base = (rowbase + (size_t)px) * 256 + d4;
    const size_t fstride = (size_t)ppf * 256;
    float4 xv[T];
#pragma unroll
    for (int f = 0; f < T; ++f) xv[f] = x[base + (size_t)f * fstride];
    if (T > 1) {
        float4 tv[T];
#pragma unroll
        for (int f = 0; f < T; ++f) tv[f] = tw[(size_t)f * 256 + d4];
#pragma unroll
        for (int f = 0; f < T; ++f) {
            nt_store4(&out[base + (size_t)f * fstride],
                      make_float4(xv[f].x + pe.x + tv[f].x,
                                  xv[f].y + pe.y + tv[f].y,
                                  xv[f].z + pe.z + tv[f].z,
                                  xv[f].w + pe.w + tv[f].w));
        }
    } else {
        nt_store4(&out[base],
                  make_float4(xv[0].x + pe.x, xv[0].y + pe.y,
                              xv[0].z + pe.z, xv[0].w + pe.w));
    }
}

__device__ __forceinline__ float4 bicubic_pe(const float4* __restrict__ wgt,
                                             int px, int out_hw, int d4) {
    const int i = px / out_hw;
    const int j = px % out_hw;
    const float scale = 64.0f / (float)out_hw;
    const float si = ((float)i + 0.5f) * scale - 0.5f;
    const float sj = ((float)j + 0.5f) * scale - 0.5f;
    const int i0 = (int)floorf(si);
    const int j0 = (int)floorf(sj);
    int ih[4], iw[4];
    float wh[4], ww[4];
#pragma unroll
    for (int a = 0; a < 4; ++a) {
        int tp = i0 - 1 + a;
        wh[a] = cubic_w(si - (float)tp);
        ih[a] = min(63, max(0, tp));
        tp = j0 - 1 + a;
        ww[a] = cubic_w(sj - (float)tp);
        iw[a] = min(63, max(0, tp));
    }
    float ax = 0.f, ay = 0.f, az = 0.f, aw = 0.f;
#pragma unroll
    for (int a = 0; a < 4; ++a) {
        float rx = 0.f, ry = 0.f, rz = 0.f, rw = 0.f;
#pragma unroll
        for (int c = 0; c < 4; ++c) {
            const float4 v = wgt[(size_t)(ih[a] * 64 + iw[c]) * 256 + d4];
            rx = fmaf(ww[c], v.x, rx);
            ry = fmaf(ww[c], v.y, ry);
            rz = fmaf(ww[c], v.z, rz);
            rw = fmaf(ww[c], v.w, rw);
        }
        ax = fmaf(wh[a], rx, ax);
        ay = fmaf(wh[a], ry, ay);
        az = fmaf(wh[a], rz, az);
        aw = fmaf(wh[a], rw, aw);
    }
    return make_float4(ax, ay, az, aw);
}

// GRIDS = [(8,32,32),(8,48,48),(4,64,64),(1,64,64)], weight (64,64,1024), dim=1024.
// One block per (grid, pixel); 256 threads; thread d4 owns float4 column d4.
__global__ __launch_bounds__(256) void posemb_add_kernel(
    const float4* __restrict__ x,     // (47104, 256) as float4
    const float4* __restrict__ wgt,   // (64*64, 256) as float4
    const float4* __restrict__ tw,    // (16, 256) as float4
    float4* __restrict__ out)         // (47104, 256) as float4
{
    const int b  = blockIdx.x;
    const int d4 = threadIdx.x;

    if (b < 1024) {              // (8,32,32), interp
        const int px = b;
        const float4 pe = bicubic_pe(wgt, px, 32, d4);
        add_frames<8>(x, tw, out, 0, 1024, px, d4, pe);
    } else if (b < 3328) {       // (8,48,48), interp
        const int px = b - 1024;
        const float4 pe = bicubic_pe(wgt, px, 48, d4);
        add_frames<8>(x, tw, out, 8192, 2304, px, d4, pe);
    } else if (b < 7424) {       // (4,64,64), direct
        const int px = b - 3328;
        const float4 pe = wgt[(size_t)px * 256 + d4];
        add_frames<4>(x, tw, out, 26624, 4096, px, d4, pe);
    } else {                     // (1,64,64), direct
        const int px = b - 7424;
        const float4 pe = wgt[(size_t)px * 256 + d4];
        add_frames<1>(x, tw, out, 43008, 4096, px, d4, pe);
    }
}

extern "C" void kernel_launch(void* const* d_in, const int* in_sizes, int n_in,
                              void* d_out, int out_size, void* d_ws, size_t ws_size,
                              hipStream_t stream) {
    const float4* x   = (const float4*)d_in[0];
    const float4* wgt = (const float4*)d_in[1];
    const float4* tw  = (const float4*)d_in[2];
    float4* out = (float4*)d_out;
    // 1024 + 2304 + 4096 + 4096 = 11520 pixel-blocks
    posemb_add_kernel<<<11520, 256, 0, stream>>>(x, wgt, tw, out);
}